// Round 13
// baseline (147.142 us; speedup 1.0000x reference)
//
#include <hip/hip_runtime.h>

typedef unsigned int u32;
typedef int i32x4 __attribute__((ext_vector_type(4)));
typedef int i32x16 __attribute__((ext_vector_type(16)));

// ws layout (bytes):
//   [0..3]      amax (float)
//   [64..1087]  256 partial maxima (float)
//   [2048..]    Wq2: fragment-major i8 weights, 768 KB:
//               addr = nt*24576 + kc*1024 + col*32 + kb
//               (n = nt*32+col in [0,1024), k = kc*32+kb in [0,768))
#define WQ_OFF 2048

__device__ __forceinline__ void gld16(const void* g, void* l) {
    __builtin_amdgcn_global_load_lds(
        (const __attribute__((address_space(1))) void*)g,
        (__attribute__((address_space(3))) void*)l, 16, 0, 0);
}

// ---------------------------------------------------------------------------
// absmax two-stage tree (no atomics)
// ---------------------------------------------------------------------------
__global__ __launch_bounds__(256) void amax_stage1(const float* __restrict__ W,
                                                   float* __restrict__ part) {
    int t = blockIdx.x * 256 + threadIdx.x;
    float v = 0.0f;
#pragma unroll
    for (int k = 0; k < 12; ++k) v = fmaxf(v, fabsf(W[t + (k << 16)]));
#pragma unroll
    for (int d = 32; d >= 1; d >>= 1) v = fmaxf(v, __shfl_xor(v, d));
    __shared__ float sm[4];
    if ((threadIdx.x & 63) == 0) sm[threadIdx.x >> 6] = v;
    __syncthreads();
    if (threadIdx.x == 0)
        part[blockIdx.x] = fmaxf(fmaxf(sm[0], sm[1]), fmaxf(sm[2], sm[3]));
}

__global__ __launch_bounds__(256) void amax_stage2(const float* __restrict__ part,
                                                   float* __restrict__ amax) {
    float v = part[threadIdx.x];
#pragma unroll
    for (int d = 32; d >= 1; d >>= 1) v = fmaxf(v, __shfl_xor(v, d));
    __shared__ float sm[4];
    if ((threadIdx.x & 63) == 0) sm[threadIdx.x >> 6] = v;
    __syncthreads();
    if (threadIdx.x == 0)
        amax[0] = fmaxf(fmaxf(sm[0], sm[1]), fmaxf(sm[2], sm[3]));
}

// ---------------------------------------------------------------------------
// quantize W_in [1024][768] f32 -> Wq2 fragment-major i8 (validated r9-r12)
// ---------------------------------------------------------------------------
__global__ __launch_bounds__(192) void quant_k(const float* __restrict__ W,
                                               const float* __restrict__ amax,
                                               u32* __restrict__ Wq4) {
    const int n = blockIdx.x, kd = threadIdx.x;     // kd: dword index 0..191
    float s = 127.0f / amax[0];
    float4 v = ((const float4*)(W + n * 768))[kd];
    int a0 = (int)rintf(v.x * s), a1 = (int)rintf(v.y * s);
    int a2 = (int)rintf(v.z * s), a3 = (int)rintf(v.w * s);
    u32 wq = (u32)(a0 & 0xFF) | ((u32)(a1 & 0xFF) << 8) |
             ((u32)(a2 & 0xFF) << 16) | ((u32)(a3 & 0xFF) << 24);
    const int nt = n >> 5, c = n & 31, kc = kd >> 3, kb4 = kd & 7;
    Wq4[nt * 6144 + kc * 256 + c * 8 + kb4] = wq;
}

// ---------------------------------------------------------------------------
// Fused forward — r12's 2-phase pipeline at 2x the occupancy.
// M=128 rows/block, 512 threads = 8 waves = 4 row-strips x 2 chunk-halves.
// Wave (s,h): 32-row strip s, chunks h*8..h*8+7 (af expansion still shared
// by the 2 n-tiles of each chunk -> total expansion VALU unchanged).
// Window = 24 KB stage (2 halves x 2 nt x 6 kc), double-buffered, 32
// windows, stage-before-compute, ONE barrier per window (r12 recipe).
// A-phase cooperative (4 thr/row) via 12 KB LDS bit-panel: x read once.
// LDS ~62 KB -> 2 blocks/CU = 16 waves/CU; launch_bounds(512,2) -> 128-reg
// cap (same 16-wave product as r8's validated (256,4), 104 used there).
// ---------------------------------------------------------------------------
__global__ __launch_bounds__(512, 2) void nnue_fwd(
    const float* __restrict__ x,       // [B][768], values in {0,1}
    const signed char* __restrict__ Wq2,
    const float* __restrict__ amax,
    const float* __restrict__ b_in,    // [1024]
    const float* __restrict__ W_h,     // [8][1024]
    const float* __restrict__ b_h,     // [8]
    const float* __restrict__ W_psqt,  // [768]
    float* __restrict__ out) {         // [B]

    // buffer layout: [ch][nt][kc 6][1 KB]; ch stride 12288, nt stride 6144
    __shared__ __align__(16) signed char bufs[2][24576];  // 48 KB
    __shared__ u32   abits[128][2][12];                   // 12 KB
    __shared__ int   bmeta[128];
    __shared__ float pmeta[128];
    __shared__ float comb[128][2];

    const int t = threadIdx.x;
    const int l = t & 63, w = t >> 6;   // 8 waves
    const int cl = l & 31, hi = l >> 5;
    const int s = w >> 1, h = w & 1;    // row-strip, chunk-half
    const size_t row0 = (size_t)blockIdx.x << 7;

    // STAGE window wn (0..31): chunk-phase p = wn&3 (kc p*6..p*6+5) of local
    // chunk lc = wn>>2 for BOTH halves. Wave w stages slabs j = w*3+i.
#define STAGE(dst, wn)                                                      \
    _Pragma("unroll")                                                       \
    for (int i = 0; i < 3; ++i) {                                           \
        int jj  = w * 3 + i;                /* 0..23 */                     \
        int chl = jj >= 12;                                                 \
        int rem = jj - (chl ? 12 : 0);                                      \
        int ntl = rem >= 6;                                                 \
        int kcl = rem - (ntl ? 6 : 0);                                      \
        int cg  = chl * 8 + ((wn) >> 2);    /* global chunk */              \
        gld16(Wq2 + (size_t)((cg << 1) + ntl) * 24576                       \
                  + (size_t)(((wn) & 3) * 6 + kcl) * 1024 + (l << 4),       \
              (signed char*)(dst) + jj * 1024);                             \
    }

    STAGE(bufs[0], 0)           // window 0 in flight under the A-phase

    // ---- A phase: 4 threads per row pack x-bits, popcount, psqt ---------
    {
        const int row = t >> 2, q = t & 3;          // q: K-quarter (192 k)
        const float4* xr = (const float4*)(x + (row0 + row) * 768) + q * 48;
        const float4* pw = (const float4*)W_psqt + q * 48;
        u32 csum = 0;
        float ps = 0.0f;
#define PKB(f) ((__float_as_uint(f.x) >> 29)         |                      \
                ((__float_as_uint(f.y) >> 29) << 8)  |                      \
                ((__float_as_uint(f.z) >> 29) << 16) |                      \
                ((__float_as_uint(f.w) >> 29) << 24))
#pragma unroll
        for (int i3 = 0; i3 < 3; ++i3) {
#pragma unroll
            for (int hh = 0; hh < 2; ++hh) {
                u32 dw = 0;
#pragma unroll
                for (int dl = 0; dl < 2; ++dl) {
                    u32 m16 = 0;
#pragma unroll
                    for (int jj = 0; jj < 4; ++jj) {
                        int fi = i3 * 16 + dl * 8 + hh * 4 + jj;
                        float4 f = xr[fi], p = pw[fi];
                        u32 d = PKB(f);
                        csum += d;                  // byte sums <= 48
                        ps = fmaf(f.x, p.x, ps); ps = fmaf(f.y, p.y, ps);
                        ps = fmaf(f.z, p.z, ps); ps = fmaf(f.w, p.w, ps);
                        m16 |= ((d * 0x01020408u) >> 24) << (jj * 4);
                    }
                    dw |= m16 << (dl * 16);
                }
                abits[row][hh][3 * q + i3] = dw;
            }
        }
#undef PKB
        int cnt = (csum & 0xFF) + ((csum >> 8) & 0xFF) +
                  ((csum >> 16) & 0xFF) + (csum >> 24);
        cnt += __shfl_xor(cnt, 1); cnt += __shfl_xor(cnt, 2);
        ps  += __shfl_xor(ps, 1);  ps  += __shfl_xor(ps, 2);
        if (q == 0) { bmeta[row] = (cnt - 1) >> 2; pmeta[row] = ps; }
    }
    __syncthreads();    // abits/meta visible; window-0 stage drained (free)

    // ---- per-lane setup -------------------------------------------------
    const int r = (s << 5) + cl;        // this lane's A row (0..127)
    u32 Ab[12];
    {
        uint4 A0 = *(const uint4*)&abits[r][hi][0];
        uint4 A1 = *(const uint4*)&abits[r][hi][4];
        uint4 A2 = *(const uint4*)&abits[r][hi][8];
        Ab[0] = A0.x; Ab[1] = A0.y; Ab[2]  = A0.z; Ab[3]  = A0.w;
        Ab[4] = A1.x; Ab[5] = A1.y; Ab[6]  = A1.z; Ab[7]  = A1.w;
        Ab[8] = A2.x; Ab[9] = A2.y; Ab[10] = A2.z; Ab[11] = A2.w;
    }

    int whoff[16];
#pragma unroll
    for (int g = 0; g < 16; ++g) {
        int er = (s << 5) + (g & 3) + ((g >> 2) << 3) + (hi << 2);
        whoff[g] = bmeta[er] << 10;             // bucket * 1024
    }

    const float sc = amax[0] * (1.0f / 127.0f);
    float rs[16];
#pragma unroll
    for (int g = 0; g < 16; ++g) rs[g] = 0.0f;

    // ---- main loop: 8 local chunks x 4 windows each ---------------------
    int bufi = 0;
    for (int lc = 0; lc < 8; ++lc) {
        i32x16 acc0 = {0,0,0,0,0,0,0,0,0,0,0,0,0,0,0,0};
        i32x16 acc1 = {0,0,0,0,0,0,0,0,0,0,0,0,0,0,0,0};
#pragma unroll
        for (int p = 0; p < 4; ++p) {
            const int wn = (lc << 2) + p;
            if (wn < 31) STAGE(bufs[bufi ^ 1], wn + 1)

            // compute this wave's half from bufs[bufi]
            const signed char* bb = bufs[bufi] + h * 12288
                                    + (cl << 5) + (hi << 4);
#pragma unroll
            for (int kcl = 0; kcl < 6; ++kcl) {
                int ks = p * 6 + kcl;
                u32 pair = Ab[ks >> 1];
                asm volatile("" : "+v"(pair));  // defeat hoist/CSE
                u32 m = (ks & 1) ? (pair >> 16) : (pair & 0xFFFFu);
                i32x4 af;
                af[0] = (int)(((m        & 0xFu) * 0x00204081u) & 0x01010101u);
                af[1] = (int)((((m >> 4) & 0xFu) * 0x00204081u) & 0x01010101u);
                af[2] = (int)((((m >> 8) & 0xFu) * 0x00204081u) & 0x01010101u);
                af[3] = (int)((((m >> 12)      ) * 0x00204081u) & 0x01010101u);
                i32x4 b0 = *(const i32x4*)(bb + (kcl << 10));
                i32x4 b1 = *(const i32x4*)(bb + 6144 + (kcl << 10));
                acc0 = __builtin_amdgcn_mfma_i32_32x32x32_i8(af, b0, acc0, 0, 0, 0);
                acc1 = __builtin_amdgcn_mfma_i32_32x32x32_i8(af, b1, acc1, 0, 0, 0);
            }

            if (p == 3) {
                // fused epilogue for global chunk c = h*8 + lc
                const int col0 = ((h << 3) + lc << 6) + cl;
                const float bi0 = b_in[col0], bi1 = b_in[col0 + 32];
#pragma unroll
                for (int g = 0; g < 16; ++g) {
                    float h0 = fminf(fmaxf(fmaf((float)acc0[g], sc, bi0), 0.f), 1.f);
                    float h1 = fminf(fmaxf(fmaf((float)acc1[g], sc, bi1), 0.f), 1.f);
                    rs[g] = fmaf(h0, W_h[whoff[g] + col0], rs[g]);
                    rs[g] = fmaf(h1, W_h[whoff[g] + col0 + 32], rs[g]);
                }
            }
            __syncthreads();
            bufi ^= 1;
        }
    }

    // ---- reduce over 32 col-lanes, combine chunk-halves, write ----------
#pragma unroll
    for (int g = 0; g < 16; ++g) {
#pragma unroll
        for (int d = 1; d < 32; d <<= 1) rs[g] += __shfl_xor(rs[g], d);
    }
    if (cl == 0) {
#pragma unroll
        for (int g = 0; g < 16; ++g) {
            int er = (s << 5) + (g & 3) + ((g >> 2) << 3) + (hi << 2);
            comb[er][h] = rs[g];
        }
    }
    __syncthreads();
    if (t < 128) {
        out[row0 + t] = comb[t][0] + comb[t][1] + pmeta[t] + b_h[bmeta[t]];
    }
}

extern "C" void kernel_launch(void* const* d_in, const int* in_sizes, int n_in,
                              void* d_out, int out_size, void* d_ws, size_t ws_size,
                              hipStream_t stream) {
    const float* x      = (const float*)d_in[0];
    const float* W_in   = (const float*)d_in[1];
    const float* b_in   = (const float*)d_in[2];
    const float* W_h    = (const float*)d_in[3];
    const float* b_h    = (const float*)d_in[4];
    const float* W_psqt = (const float*)d_in[5];
    float* out = (float*)d_out;

    float* amax = (float*)d_ws;
    float* part = (float*)((char*)d_ws + 64);
    signed char* Wq2 = (signed char*)d_ws + WQ_OFF;     // 768 KB

    amax_stage1<<<256, 256, 0, stream>>>(W_in, part);
    amax_stage2<<<1, 256, 0, stream>>>(part, amax);
    quant_k<<<1024, 192, 0, stream>>>(W_in, amax, (u32*)Wq2);

    int B = out_size;                   // 65536
    nnue_fwd<<<B / 128, 512, 0, stream>>>(x, Wq2, amax, b_in, W_h, b_h,
                                          W_psqt, out);
}